// Round 1
// baseline (176.768 us; speedup 1.0000x reference)
//
#include <hip/hip_runtime.h>
#include <hip/hip_bf16.h>

// ---------------------------------------------------------------------------
// LocalAttention R12: swap qkv_k (128^2 2-barrier, 583 TF measured) for the
// 256^2 8-phase counted-vmcnt template (T1+T2+T3+T4+T5 per guide m201):
//   - 8 waves (2M x 4N, interleaved ownership: wave rows = mh*128+wr*64,
//     cols = nh*128+wc*32) so each phase (mh,nh) reads exactly ONE A-half +
//     ONE B-half -> mid-tile half-tile restaging is race-free by barrier.
//   - BK=64, 2 K-tiles/iter, 16 MFMA/phase, LDS 128 KiB double-buffered.
//   - raw s_barrier (never __syncthreads in loop -> no vmcnt(0) drain);
//     s_waitcnt vmcnt(4) only at phases 4 and 8.
//   - bank swizzle via pre-swizzled GLOBAL source (col ^= (row&7)*8 elems)
//     + same XOR on ds_read address (rule #21 both-sides involution).
//   - bijective XCD swizzle: 192 blocks % 8 == 0.
// prep_k / attn_k / wo_k are byte-identical to the verified R11 kernels.
// Prediction: qkv 44.2us -> 22-28us; total 172 -> ~150-156us.
// ---------------------------------------------------------------------------

typedef __attribute__((ext_vector_type(8))) short bf16x8;
typedef __attribute__((ext_vector_type(4))) float f32x4;

#define S_LEN 4096
#define D_MODEL 1024
#define N_HEADS 16
#define HEAD_DIM 64
#define WINDOW 256
#define QKV_LD 3072

static __device__ __forceinline__ unsigned short f2bfbits(float f) {
    __hip_bfloat16 h = __float2bfloat16(f);
    unsigned short u;
    __builtin_memcpy(&u, &h, sizeof(u));
    return u;
}

typedef const __attribute__((address_space(1))) void c_gvoid;
typedef __attribute__((address_space(3))) void lvoid;
static __device__ __forceinline__ void gload16(const void* g, void* l) {
    __builtin_amdgcn_global_load_lds((c_gvoid*)g, (lvoid*)l, 16, 0, 0);
}

// ---------------- fused prep: x-cast, W transposes, bias concat (R8) --------
__global__ __launch_bounds__(256) void prep_k(const float* __restrict__ x,
                                              const float* __restrict__ Wq,
                                              const float* __restrict__ Wk,
                                              const float* __restrict__ Wv,
                                              const float* __restrict__ Wo,
                                              const float* __restrict__ bq,
                                              const float* __restrict__ bk,
                                              const float* __restrict__ bv,
                                              unsigned short* __restrict__ xb,
                                              __hip_bfloat16* __restrict__ Wqkvt,
                                              __hip_bfloat16* __restrict__ Wot,
                                              float* __restrict__ bias_cat) {
    const int b = blockIdx.x;
    const int t = threadIdx.x;
    if (b < 2048) {
        int i = b * 2048 + t * 8;
        float4 v0 = *(const float4*)(x + i);
        float4 v1 = *(const float4*)(x + i + 4);
        ushort4 o0, o1;
        o0.x = f2bfbits(v0.x); o0.y = f2bfbits(v0.y);
        o0.z = f2bfbits(v0.z); o0.w = f2bfbits(v0.w);
        o1.x = f2bfbits(v1.x); o1.y = f2bfbits(v1.y);
        o1.z = f2bfbits(v1.z); o1.w = f2bfbits(v1.w);
        *(ushort4*)(xb + i) = o0;
        *(ushort4*)(xb + i + 4) = o1;
        return;
    }
    if (b < 3072) {
        __shared__ __hip_bfloat16 tile[64][65];
        const int m = (b - 2048) >> 8;
        const int tid = (b - 2048) & 255;
        const int n0 = (tid & 15) * 64, k0 = (tid >> 4) * 64;
        const float* src = (m == 0) ? Wq : (m == 1) ? Wk : (m == 2) ? Wv : Wo;
        __hip_bfloat16* dst = (m < 3) ? (Wqkvt + (size_t)m * D_MODEL * D_MODEL) : Wot;
        for (int c = t; c < 1024; c += 256) {
            int r = c >> 4, c4 = (c & 15) * 4;
            float4 v = *(const float4*)(src + (size_t)(k0 + r) * D_MODEL + n0 + c4);
            tile[r][c4 + 0] = __float2bfloat16(v.x);
            tile[r][c4 + 1] = __float2bfloat16(v.y);
            tile[r][c4 + 2] = __float2bfloat16(v.z);
            tile[r][c4 + 3] = __float2bfloat16(v.w);
        }
        __syncthreads();
        for (int c = t; c < 1024; c += 256) {
            int rr = c >> 4, c4 = (c & 15) * 4;
            ushort4 o;
            unsigned short u0, u1, u2, u3;
            __builtin_memcpy(&u0, &tile[c4 + 0][rr], 2);
            __builtin_memcpy(&u1, &tile[c4 + 1][rr], 2);
            __builtin_memcpy(&u2, &tile[c4 + 2][rr], 2);
            __builtin_memcpy(&u3, &tile[c4 + 3][rr], 2);
            o.x = u0; o.y = u1; o.z = u2; o.w = u3;
            *(ushort4*)((unsigned short*)dst + (size_t)(n0 + rr) * D_MODEL + k0 + c4) = o;
        }
        return;
    }
    for (int c = t; c < 3 * D_MODEL; c += 256) {
        float v = (c < 1024) ? bq[c] : (c < 2048) ? bk[c - 1024] : bv[c - 2048];
        bias_cat[c] = v;
    }
}

// ---------------- QKV GEMM: 256^2 8-phase counted-vmcnt (R12) ---------------
// C[4096][3072] = xb[4096][1024] * Wqkvt[3072][1024]^T + bcat, bf16 out.
// Stage slots per iteration (tiles T0=kt@buf0, T1=kt+1@buf1):
//  P1:buf1.AH(T1) P2:buf1.BH(T1) P3:buf0.AL(T0+2) P4:buf0.BL(T0+2)+vmcnt(4)
//  P5:buf0.AH(T0+2) P6:buf0.BH(T0+2) P7:buf1.AL(T1+2) P8:buf1.BL(T1+2)+vmcnt(4)
// Each half freed exactly one phase before its stage slot (see ownership map).
__global__ __launch_bounds__(512, 2) void qkv256_k(const __hip_bfloat16* __restrict__ A,
                                                   const __hip_bfloat16* __restrict__ Bt,
                                                   const float* __restrict__ bias,
                                                   __hip_bfloat16* __restrict__ Cout) {
    __shared__ __align__(16) char lds[131072];  // [buf2][A 32KB | B 32KB]

    // bijective XCD swizzle: 192 = 8 * 24
    const int bid = blockIdx.x;
    const int wg = (bid & 7) * 24 + (bid >> 3);
    const int by = wg / 12, bx = wg % 12;
    const int m0 = by * 256, n0 = bx * 256;

    const int t = threadIdx.x;
    const int w = t >> 6, lane = t & 63;
    const int wr = w >> 2, wc = w & 3;          // 2M x 4N waves
    const int quad = lane >> 4, l16 = lane & 15;

    // staging: dest is linear (gload_lds), source col pre-swizzled by row&7
    const int ls = lane >> 3, lc = lane & 7;
    const int swz = (lc ^ ls) << 3;             // element column 0..56
    const __hip_bfloat16* gA = A + (size_t)(m0 + w * 16 + ls) * D_MODEL + swz;
    const __hip_bfloat16* gB = Bt + (size_t)(n0 + w * 16 + ls) * D_MODEL + swz;
    const int dbase = w * 2048 + lane * 16;     // bytes within half-tile region

    // ds_read addresses: byte = row*128 + ((kk*64 + quad*16) ^ ((row&7)<<4))
    const int h3 = l16 & 7;
    const int colb0 = (quad ^ h3) << 4;
    const int aoff0 = (wr * 64 + l16) * 128 + colb0;
    const int aoff1 = aoff0 ^ 64;
    const int boff0 = 32768 + (wc * 32 + l16) * 128 + colb0;
    const int boff1 = boff0 ^ 64;

    f32x4 acc[8][4];
#pragma unroll
    for (int i = 0; i < 8; ++i)
#pragma unroll
        for (int j = 0; j < 4; ++j) acc[i][j] = (f32x4){0.f, 0.f, 0.f, 0.f};

#define ST_A(BUF, KT, HF)                                                      \
    {                                                                          \
        const __hip_bfloat16* s_ = gA + (size_t)((HF) * 128) * D_MODEL + (KT) * 64; \
        char* d_ = lds + ((BUF) * 65536 + (HF) * 16384 + dbase);               \
        gload16(s_, d_);                                                       \
        gload16(s_ + 8 * D_MODEL, d_ + 1024);                                  \
    }
#define ST_B(BUF, KT, HF)                                                      \
    {                                                                          \
        const __hip_bfloat16* s_ = gB + (size_t)((HF) * 128) * D_MODEL + (KT) * 64; \
        char* d_ = lds + ((BUF) * 65536 + 32768 + (HF) * 16384 + dbase);       \
        gload16(s_, d_);                                                       \
        gload16(s_ + 8 * D_MODEL, d_ + 1024);                                  \
    }

#define PHASE(BUF, MH, NH, STAGE_CODE, TAILWAIT)                               \
    {                                                                          \
        __builtin_amdgcn_sched_barrier(0);                                     \
        bf16x8 a_[4][2], b_[2][2];                                             \
        const char* ab_ = lds + ((BUF) * 65536 + (MH) * 16384);                \
        const char* bb_ = lds + ((BUF) * 65536 + (NH) * 16384);                \
        _Pragma("unroll") for (int i_ = 0; i_ < 4; ++i_) {                     \
            a_[i_][0] = *(const bf16x8*)(ab_ + aoff0 + i_ * 2048);             \
            a_[i_][1] = *(const bf16x8*)(ab_ + aoff1 + i_ * 2048);             \
        }                                                                      \
        _Pragma("unroll") for (int j_ = 0; j_ < 2; ++j_) {                     \
            b_[j_][0] = *(const bf16x8*)(bb_ + boff0 + j_ * 2048);             \
            b_[j_][1] = *(const bf16x8*)(bb_ + boff1 + j_ * 2048);             \
        }                                                                      \
        STAGE_CODE;                                                            \
        TAILWAIT;                                                              \
        __builtin_amdgcn_sched_barrier(0);                                     \
        __builtin_amdgcn_s_barrier();                                          \
        asm volatile("s_waitcnt lgkmcnt(0)" ::: "memory");                     \
        __builtin_amdgcn_sched_barrier(0);                                     \
        __builtin_amdgcn_s_setprio(1);                                         \
        _Pragma("unroll") for (int i_ = 0; i_ < 4; ++i_)                       \
            _Pragma("unroll") for (int j_ = 0; j_ < 2; ++j_) {                 \
                acc[(MH) * 4 + i_][(NH) * 2 + j_] =                            \
                    __builtin_amdgcn_mfma_f32_16x16x32_bf16(                   \
                        a_[i_][0], b_[j_][0], acc[(MH) * 4 + i_][(NH) * 2 + j_], 0, 0, 0); \
                acc[(MH) * 4 + i_][(NH) * 2 + j_] =                            \
                    __builtin_amdgcn_mfma_f32_16x16x32_bf16(                   \
                        a_[i_][1], b_[j_][1], acc[(MH) * 4 + i_][(NH) * 2 + j_], 0, 0, 0); \
            }                                                                  \
        __builtin_amdgcn_s_setprio(0);                                         \
        __builtin_amdgcn_sched_barrier(0);                                     \
        __builtin_amdgcn_s_barrier();                                          \
    }

    // prologue: tile0 complete + tile1 AL,BL; allow tile1's 4 loads in flight
    ST_A(0, 0, 0); ST_B(0, 0, 0); ST_A(0, 0, 1); ST_B(0, 0, 1);
    ST_A(1, 1, 0); ST_B(1, 1, 0);
    asm volatile("s_waitcnt vmcnt(4)" ::: "memory");
    __builtin_amdgcn_sched_barrier(0);
    __builtin_amdgcn_s_barrier();

    for (int kt = 0; kt < 16; kt += 2) {
        const bool g2 = (kt + 2) < 16;
        const bool g3 = (kt + 3) < 16;
        PHASE(0, 0, 0, { ST_A(1, kt + 1, 1); }, {});
        PHASE(0, 0, 1, { ST_B(1, kt + 1, 1); }, {});
        PHASE(0, 1, 0, { if (g2) ST_A(0, kt + 2, 0); }, {});
        PHASE(0, 1, 1, { if (g2) ST_B(0, kt + 2, 0); },
              { if (g2) { asm volatile("s_waitcnt vmcnt(4)" ::: "memory"); }
                else    { asm volatile("s_waitcnt vmcnt(0)" ::: "memory"); } });
        PHASE(1, 0, 0, { if (g2) ST_A(0, kt + 2, 1); }, {});
        PHASE(1, 0, 1, { if (g2) ST_B(0, kt + 2, 1); }, {});
        PHASE(1, 1, 0, { if (g3) ST_A(1, kt + 3, 0); }, {});
        PHASE(1, 1, 1, { if (g3) ST_B(1, kt + 3, 0); },
              { if (g3) { asm volatile("s_waitcnt vmcnt(4)" ::: "memory"); }
                else    { asm volatile("s_waitcnt vmcnt(0)" ::: "memory"); } });
    }

#undef PHASE
#undef ST_A
#undef ST_B

    // epilogue: C row = frag_row + quad*4 + r, col = frag_col + l16 (verified)
#pragma unroll
    for (int mh = 0; mh < 2; ++mh)
#pragma unroll
        for (int i = 0; i < 4; ++i) {
            const int row0 = m0 + mh * 128 + wr * 64 + i * 16 + quad * 4;
#pragma unroll
            for (int nh = 0; nh < 2; ++nh)
#pragma unroll
                for (int j = 0; j < 2; ++j) {
                    const int col = n0 + nh * 128 + wc * 32 + j * 16 + l16;
                    const float bv = bias[col];
                    const f32x4 v = acc[mh * 4 + i][nh * 2 + j];
#pragma unroll
                    for (int r = 0; r < 4; ++r)
                        Cout[(size_t)(row0 + r) * QKV_LD + col] =
                            __float2bfloat16(v[r] + bv);
                }
        }
}

// ---------------- Wo GEMM: R8's 128x64 swapped/float4 (verified) ------------
__global__ __launch_bounds__(256) void wo_k(const __hip_bfloat16* __restrict__ A,
                                            const __hip_bfloat16* __restrict__ Bt,
                                            const float* __restrict__ bias,
                                            float* __restrict__ Cout) {
    constexpr int TM = 128, TN = 64, K = D_MODEL, N = D_MODEL;
    constexpr int MI = 4, NI = 2;
    __shared__ __align__(16) __hip_bfloat16 As[TM * 32];
    __shared__ __align__(16) __hip_bfloat16 Bs[TN * 32];

    const int m0 = blockIdx.y * TM, n0 = blockIdx.x * TN;
    const int t = threadIdx.x;
    const int wave = t >> 6, lane = t & 63;
    const int quad = lane >> 4, l16 = lane & 15;
    const int wm = (wave & 1) * (TM / 2), wn = (wave >> 1) * (TN / 2);

    const int srow = t >> 2;
    const int scol = (t & 3) * 8;

    f32x4 acc[MI][NI];
#pragma unroll
    for (int mi = 0; mi < MI; ++mi)
#pragma unroll
        for (int ni = 0; ni < NI; ++ni) acc[mi][ni] = (f32x4){0.f, 0.f, 0.f, 0.f};

    const __hip_bfloat16* gA = A + (size_t)(m0 + srow) * K + scol;
    const __hip_bfloat16* gB = Bt + (size_t)(n0 + srow) * K + scol;

    for (int k0 = 0; k0 < K; k0 += 32) {
#pragma unroll
        for (int p = 0; p < TM / 64; ++p)
            gload16(gA + (size_t)(p * 64) * K + k0, &As[p * 2048 + t * 8]);
        if (t < 128)
            ;
        gload16(gB + k0, &Bs[t * 8 >= TN * 32 ? 0 : t * 8]);
        __syncthreads();

        bf16x8 af[MI], bfr[NI];
#pragma unroll
        for (int mi = 0; mi < MI; ++mi)
            af[mi] = *(const bf16x8*)&As[(wm + mi * 16 + l16) * 32 + quad * 8];
#pragma unroll
        for (int ni = 0; ni < NI; ++ni)
            bfr[ni] = *(const bf16x8*)&Bs[(wn + ni * 16 + l16) * 32 + quad * 8];
#pragma unroll
        for (int mi = 0; mi < MI; ++mi)
#pragma unroll
            for (int ni = 0; ni < NI; ++ni)
                acc[mi][ni] = __builtin_amdgcn_mfma_f32_16x16x32_bf16(
                    bfr[ni], af[mi], acc[mi][ni], 0, 0, 0);
        __syncthreads();
    }

    float4 bv[NI];
#pragma unroll
    for (int ni = 0; ni < NI; ++ni)
        bv[ni] = *(const float4*)&bias[n0 + wn + ni * 16 + quad * 4];
#pragma unroll
    for (int mi = 0; mi < MI; ++mi) {
        const int row = m0 + wm + mi * 16 + l16;
#pragma unroll
        for (int ni = 0; ni < NI; ++ni) {
            const int col = n0 + wn + ni * 16 + quad * 4;
            float4 o;
            o.x = acc[mi][ni][0] + bv[ni].x;
            o.y = acc[mi][ni][1] + bv[ni].y;
            o.z = acc[mi][ni][2] + bv[ni].z;
            o.w = acc[mi][ni][3] + bv[ni].w;
            *(float4*)(Cout + (size_t)row * N + col) = o;
        }
    }
}

// ---------------- sliding-window flash attention, 128-q blocks (R8) ---------
__global__ __launch_bounds__(256) void attn_k(const __hip_bfloat16* __restrict__ QKV,
                                              __hip_bfloat16* __restrict__ AO) {
    __shared__ __align__(16) __hip_bfloat16 Qs[128 * 64];   // 16 KB, XOR-8 rows
    __shared__ __align__(16) __hip_bfloat16 Ks[64 * 64];    // 8 KB, XOR-8 rows
    __shared__ __align__(16) __hip_bfloat16 Vt[64 * 72];    // [hd][key], padded
    __shared__ __align__(16) __hip_bfloat16 Ps[128 * 72];   // [q][key], padded

    const int h = blockIdx.y;
    const int i0 = blockIdx.x * 128;
    const int t = threadIdx.x;
    const int wave = t >> 6, lane = t & 63;
    const int quad = lane >> 4, l16 = lane & 15;
    const float sc = 0.125f * 1.44269504088896f;  // 1/sqrt(64) * log2(e)

    const __hip_bfloat16* Q = QKV + h * HEAD_DIM;
    const __hip_bfloat16* K = QKV + D_MODEL + h * HEAD_DIM;
    const __hip_bfloat16* V = QKV + 2 * D_MODEL + h * HEAD_DIM;

    const int grow = t >> 3;                       // 0..31
    const int glog = ((t & 7) ^ ((t >> 3) & 7)) * 8;
#pragma unroll
    for (int p = 0; p < 4; ++p)
        gload16(Q + (size_t)(i0 + p * 32 + grow) * QKV_LD + glog,
                &Qs[p * 2048 + t * 8]);
    __syncthreads();

    const int rq0 = wave * 32 + l16;     // lane's two q rows: rq0, rq0+16
    bf16x8 aq[2][2];
#pragma unroll
    for (int m = 0; m < 2; ++m) {
        const int rq = rq0 + m * 16;
#pragma unroll
        for (int kk = 0; kk < 2; ++kk)
            aq[m][kk] = *(const bf16x8*)&Qs[rq * 64 + ((kk * 4 + quad) ^ (rq & 7)) * 8];
    }

    float m_i[2] = {-3.0e38f, -3.0e38f}, l_i[2] = {0.f, 0.f};
    f32x4 Ov[2][4];
#pragma unroll
    for (int m = 0; m < 2; ++m)
#pragma unroll
        for (int no = 0; no < 4; ++no) Ov[m][no] = (f32x4){0.f, 0.f, 0.f, 0.f};

    const int vp = t >> 3, vc = t & 7;

    for (int tt = 0; tt < 6; ++tt) {
        const int tb = i0 - WINDOW + tt * 64;
        if (tb < 0) continue;  // uniform across block

#pragma unroll
        for (int p = 0; p < 2; ++p)
            gload16(K + (size_t)(tb + p * 32 + grow) * QKV_LD + glog,
                    &Ks[p * 2048 + t * 8]);
        {
            uint4 v0 = *(const uint4*)(V + (size_t)(tb + 2 * vp) * QKV_LD + vc * 8);
            uint4 v1 = *(const uint4*)(V + (size_t)(tb + 2 * vp + 1) * QKV_LD + vc * 8);
            const unsigned short* a0 = (const unsigned short*)&v0;
            const unsigned short* a1 = (const unsigned short*)&v1;
#pragma unroll
            for (int j = 0; j < 8; ++j) {
                unsigned int pk = (unsigned int)a0[j] | ((unsigned int)a1[j] << 16);
                *(unsigned int*)&Vt[(vc * 8 + j) * 72 + 2 * vp] = pk;
            }
        }
        __syncthreads();

        f32x4 s[2][4];
#pragma unroll
        for (int m = 0; m < 2; ++m)
#pragma unroll
            for (int ni = 0; ni < 4; ++ni) s[m][ni] = (f32x4){0.f, 0.f, 0.f, 0.f};
#pragma unroll
        for (int kk = 0; kk < 2; ++kk)
#pragma unroll
            for (int ni = 0; ni < 4; ++ni) {
                int rk = ni * 16 + l16;
                bf16x8 bk = *(const bf16x8*)&Ks[rk * 64 + ((kk * 4 + quad) ^ (rk & 7)) * 8];
#pragma unroll
                for (int m = 0; m < 2; ++m)
                    s[m][ni] = __builtin_amdgcn_mfma_f32_16x16x32_bf16(
                        bk, aq[m][kk], s[m][ni], 0, 0, 0);
            }

#pragma unroll
        for (int m = 0; m < 2; ++m) {
            const int qi = i0 + rq0 + m * 16;
            float mx = -3.0e38f;
#pragma unroll
            for (int ni = 0; ni < 4; ++ni)
#pragma unroll
                for (int r = 0; r < 4; ++r) {
                    int j = tb + ni * 16 + quad * 4 + r;
                    float v = s[m][ni][r] * sc;
                    bool ok = (j <= qi) && (qi - j < WINDOW);
                    v = ok ? v : -3.0e38f;
                    s[m][ni][r] = v;
                    mx = fmaxf(mx, v);
                }
            mx = fmaxf(mx, __shfl_xor(mx, 16));
            mx = fmaxf(mx, __shfl_xor(mx, 32));
            const float mn = fmaxf(m_i[m], mx);
            const float alpha = exp2f(m_i[m] - mn);
            m_i[m] = mn;
            float sum = 0.f;
#pragma unroll
            for (int ni = 0; ni < 4; ++ni)
#pragma unroll
                for (int r = 0; r < 4; ++r) {
                    float e = exp2f(s[m][ni][r] - mn);
                    s[m][ni][r] = e;
                    sum += e;
                }
            sum += __shfl_xor(sum, 16);
            sum += __shfl_xor(sum, 32);
            l_i[m] = l_i[m] * alpha + sum;
#pragma unroll
            for (int no = 0; no < 4; ++no) Ov[m][no] *= alpha;

            const int rq = rq0 + m * 16;
#pragma unroll
            for (int ni = 0; ni < 4; ++ni) {
                ushort4 w4;
                w4.x = f2bfbits(s[m][ni][0]); w4.y = f2bfbits(s[m][ni][1]);
                w4.z = f2bfbits(s[m][ni][2]); w4.w = f2bfbits(s[m][ni][3]);
                *(ushort4*)&Ps[rq * 72 + ni * 16 + quad * 4] = w4;
            }
        }

#pragma unroll
        for (int kk = 0; kk < 2; ++kk) {
            bf16x8 ap[2];
#pragma unroll
            for (int m = 0; m < 2; ++m)
                ap[m] = *(const bf16x8*)&Ps[(rq0 + m * 16) * 72 + kk * 32 + quad * 8];
#pragma unroll
            for (int no = 0; no < 4; ++no) {
                bf16x8 bvv = *(const bf16x8*)&Vt[(no * 16 + l16) * 72 + kk * 32 + quad * 8];
#pragma unroll
                for (int m = 0; m < 2; ++m)
                    Ov[m][no] = __builtin_amdgcn_mfma_f32_16x16x32_bf16(
                        bvv, ap[m], Ov[m][no], 0, 0, 0);
            }
        }
        __syncthreads();
    }

#pragma unroll
    for (int m = 0; m < 2; ++m) {
        const float inv = 1.0f / l_i[m];
        const int qi = i0 + rq0 + m * 16;
#pragma unroll
        for (int no = 0; no < 4; ++no) {
            ushort4 o;
            o.x = f2bfbits(Ov[m][no][0] * inv);
            o.y = f2bfbits(Ov[m][no][1] * inv);
            o.z = f2bfbits(Ov[m][no][2] * inv);
            o.w = f2bfbits(Ov[m][no][3] * inv);
            *(ushort4*)((unsigned short*)AO + (size_t)qi * D_MODEL + h * HEAD_DIM +
                        no * 16 + quad * 4) = o;
        }
    }
}

// ---------------------------------------------------------------------------
extern "C" void kernel_launch(void* const* d_in, const int* in_sizes, int n_in,
                              void* d_out, int out_size, void* d_ws, size_t ws_size,
                              hipStream_t stream) {
    const float* x  = (const float*)d_in[0];
    const float* Wq = (const float*)d_in[1];
    const float* Wk = (const float*)d_in[2];
    const float* Wv = (const float*)d_in[3];
    const float* Wo = (const float*)d_in[4];
    const float* bq = (const float*)d_in[5];
    const float* bk = (const float*)d_in[6];
    const float* bv = (const float*)d_in[7];
    const float* bo = (const float*)d_in[8];
    float* out = (float*)d_out;

    char* w = (char*)d_ws;
    const size_t MB = 1u << 20;
    __hip_bfloat16* xb    = (__hip_bfloat16*)(w + 0 * MB);   // 8 MB
    __hip_bfloat16* Wqkvt = (__hip_bfloat16*)(w + 8 * MB);   // 6 MB [3072][1024]
    __hip_bfloat16* Wot   = (__hip_bfloat16*)(w + 14 * MB);  // 2 MB
    float*          bcat  = (float*)(w + 16 * MB);           // 12 KB
    __hip_bfloat16* QKV   = (__hip_bfloat16*)(w + 17 * MB);  // 24 MB [4096][3072]
    __hip_bfloat16* AO    = (__hip_bfloat16*)(w + 41 * MB);  // 8 MB, end 49 MB

    prep_k<<<3073, 256, 0, stream>>>(x, Wq, Wk, Wv, Wo, bq, bk, bv,
                                     (unsigned short*)xb, Wqkvt, Wot, bcat);

    qkv256_k<<<192, 512, 0, stream>>>(xb, Wqkvt, bcat, QKV);

    dim3 ag(S_LEN / 128, N_HEADS);
    attn_k<<<ag, 256, 0, stream>>>(QKV, AO);

    dim3 go(D_MODEL / 64, S_LEN / 128);
    wo_k<<<go, 256, 0, stream>>>(AO, Wot, bo, out);
}